// Round 3
// baseline (348.985 us; speedup 1.0000x reference)
//
#include <hip/hip_runtime.h>
#include <math.h>

#define CCH 512
#define NH 4
#define HD 128
#define HW 1024
#define BATCH 16
#define EPS 1e-5f

typedef __attribute__((ext_vector_type(8))) short bfrag;   // 8 bf16 = 4 VGPRs
typedef __attribute__((ext_vector_type(4))) float f4;

static __device__ __forceinline__ unsigned short f2bf(float f) {
  union { float f; unsigned u; } v;
  v.f = f;
  unsigned r = v.u + 0x7fff + ((v.u >> 16) & 1);  // RNE
  return (unsigned short)(r >> 16);
}
static __device__ __forceinline__ unsigned pack2(unsigned short a, unsigned short b) {
  return (unsigned)a | ((unsigned)b << 16);
}
// async global->LDS, 16B/lane. LDS dest = wave-uniform base + lane*16.
static __device__ __forceinline__ void ldg_lds16(const unsigned short* g,
                                                 unsigned short* l) {
  __builtin_amdgcn_global_load_lds(
      (const __attribute__((address_space(1))) unsigned int*)g,
      (__attribute__((address_space(3))) unsigned int*)l, 16, 0, 0);
}

// ---------- weights fp32 -> bf16 (4 matrices stacked) ----------
__global__ __launch_bounds__(256) void wcvt_kernel(const float* __restrict__ s0,
                                                   const float* __restrict__ s1,
                                                   const float* __restrict__ s2,
                                                   const float* __restrict__ s3,
                                                   unsigned short* __restrict__ d) {
  const float* srcs[4] = {s0, s1, s2, s3};
  const float* s = srcs[blockIdx.y];
  unsigned short* dp = d + (size_t)blockIdx.y * CCH * CCH;
  int i = blockIdx.x * 256 + threadIdx.x;
  f4 v = ((const f4*)s)[i];
  ushort4 o;
  o.x = f2bf(v.x); o.y = f2bf(v.y); o.z = f2bf(v.z); o.w = f2bf(v.w);
  ((ushort4*)dp)[i] = o;
}

// ---------- GroupNorm -> position-major bf16 hn_t[b][hw][c] ----------
__global__ __launch_bounds__(256) void gn_kernel(const float* __restrict__ x,
                                                 const float* __restrict__ gamma,
                                                 const float* __restrict__ beta,
                                                 unsigned short* __restrict__ hn) {
  int b = blockIdx.x >> 5, g = blockIdx.x & 31;
  const float* xp = x + ((size_t)b * CCH + g * 16) * HW;
  int t = threadIdx.x;
  float s = 0.f, ss = 0.f;
  const f4* xp4 = (const f4*)xp;
  for (int i = t; i < 4096; i += 256) {
    f4 v = xp4[i];
    s += v.x + v.y + v.z + v.w;
    ss += v.x * v.x + v.y * v.y + v.z * v.z + v.w * v.w;
  }
#pragma unroll
  for (int off = 32; off > 0; off >>= 1) {
    s += __shfl_xor(s, off);
    ss += __shfl_xor(ss, off);
  }
  __shared__ float rs[4], rss[4];
  int w = t >> 6;
  if ((t & 63) == 0) { rs[w] = s; rss[w] = ss; }
  __syncthreads();
  s = rs[0] + rs[1] + rs[2] + rs[3];
  ss = rss[0] + rss[1] + rss[2] + rss[3];
  const float invn = 1.f / (16 * HW);
  float mean = s * invn;
  float var = ss * invn - mean * mean;
  float rstd = rsqrtf(var + EPS);
  float a_[16], b_[16];
#pragma unroll
  for (int c = 0; c < 16; ++c) {
    float gm = gamma[g * 16 + c] * rstd;
    a_[c] = gm;
    b_[c] = beta[g * 16 + c] - mean * gm;
  }
#pragma unroll
  for (int i = 0; i < 4; ++i) {
    int p = t + 256 * i;
    unsigned short tv[16];
#pragma unroll
    for (int c = 0; c < 16; ++c) tv[c] = f2bf(xp[c * HW + p] * a_[c] + b_[c]);
    uint4 u0, u1;
    u0.x = pack2(tv[0], tv[1]);  u0.y = pack2(tv[2], tv[3]);
    u0.z = pack2(tv[4], tv[5]);  u0.w = pack2(tv[6], tv[7]);
    u1.x = pack2(tv[8], tv[9]);  u1.y = pack2(tv[10], tv[11]);
    u1.z = pack2(tv[12], tv[13]); u1.w = pack2(tv[14], tv[15]);
    unsigned short* dst = hn + ((size_t)b * HW + p) * CCH + g * 16;
    *(uint4*)dst = u0;
    *(uint4*)(dst + 8) = u1;
  }
}

// ---------- MFMA GEMM, m97-style staging (global_load_lds + XOR swizzle) ---
// D[pos][ch] = sum_k Xt[b][pos][k] * W[ch][k] + bias
// PROJ=0: fused QKV (c0g in [0,1536)): mat 0,1 -> pos-major bf16 (Q,K);
//         mat 2 -> ch-major bf16 (V).
// PROJ=1: fp32 ch-major out + residual.
template <int PROJ>
__global__ __launch_bounds__(256, 3) void mm_kernel(
    const unsigned short* __restrict__ Xt, const unsigned short* __restrict__ Wb,
    const float* __restrict__ b0, const float* __restrict__ b1,
    const float* __restrict__ b2, const float* __restrict__ resid,
    unsigned short* __restrict__ O0, unsigned short* __restrict__ O1,
    unsigned short* __restrict__ O2, float* __restrict__ Ofp) {
  int b = blockIdx.z;
  int p0 = blockIdx.x * 128;   // x fastest: same (b,p-strip) blocks land on one XCD
  int c0g = blockIdx.y * 128;
  __shared__ __align__(16) unsigned short Xs[128 * 32];
  __shared__ __align__(16) unsigned short Ws[128 * 32];
  int t = threadIdx.x;
  int w = t >> 6, lane = t & 63, l15 = lane & 15, quad = lane >> 4;
  int wp = (w & 1) * 64, wc = (w >> 1) * 64;
  const unsigned short* Xb = Xt + (size_t)b * HW * CCH;
  const unsigned short* Wr = Wb + (size_t)c0g * CCH;
  f4 acc[4][4] = {};
  for (int k0 = 0; k0 < CCH; k0 += 32) {
    __syncthreads();
#pragma unroll
    for (int j = 0; j < 2; ++j) {
      int chk = w * 2 + j;             // 1KB chunk = 16 rows x 64B
      int r = chk * 16 + (lane >> 2);
      int c = (lane & 3) ^ (r & 3);    // XOR swizzle
      ldg_lds16(&Xb[(size_t)(p0 + r) * CCH + k0 + c * 8], &Xs[chk * 512]);
      ldg_lds16(&Wr[(size_t)r * CCH + k0 + c * 8], &Ws[chk * 512]);
    }
    __syncthreads();
    bfrag af[4], bf[4];
#pragma unroll
    for (int pt = 0; pt < 4; ++pt) {
      int r = wp + pt * 16 + l15;
      af[pt] = *(const bfrag*)&Xs[r * 32 + (quad ^ (r & 3)) * 8];
    }
#pragma unroll
    for (int ct = 0; ct < 4; ++ct) {
      int r = wc + ct * 16 + l15;
      bf[ct] = *(const bfrag*)&Ws[r * 32 + (quad ^ (r & 3)) * 8];
    }
#pragma unroll
    for (int pt = 0; pt < 4; ++pt)
#pragma unroll
      for (int ct = 0; ct < 4; ++ct)
        acc[pt][ct] = __builtin_amdgcn_mfma_f32_16x16x32_bf16(
            af[pt], bf[ct], acc[pt][ct], 0, 0, 0);
  }
  if (PROJ) {
#pragma unroll
    for (int ct = 0; ct < 4; ++ct) {
      int ch = c0g + wc + ct * 16 + l15;
      float bi = b0[ch];
#pragma unroll
      for (int pt = 0; pt < 4; ++pt) {
        int pos = p0 + wp + pt * 16 + quad * 4;
        f4 v = acc[pt][ct];
        size_t off = (size_t)b * CCH * HW + (size_t)ch * HW + pos;
        float4 rv = *(const float4*)&resid[off];
        float4 st;
        st.x = v.x + bi + rv.x; st.y = v.y + bi + rv.y;
        st.z = v.z + bi + rv.z; st.w = v.w + bi + rv.w;
        *(float4*)&Ofp[off] = st;
      }
    }
  } else {
    int mat = c0g >> 9;
    int c0 = c0g & 511;
    const float* bias = mat == 0 ? b0 : (mat == 1 ? b1 : b2);
    unsigned short* O = mat == 0 ? O0 : (mat == 1 ? O1 : O2);
#pragma unroll
    for (int ct = 0; ct < 4; ++ct) {
      int ch = c0 + wc + ct * 16 + l15;
      float bi = bias[ch];
#pragma unroll
      for (int pt = 0; pt < 4; ++pt) {
        int pos = p0 + wp + pt * 16 + quad * 4;
        f4 v = acc[pt][ct];
        if (mat < 2) {  // pos-major
          unsigned short* Op = O + (size_t)b * HW * CCH;
          Op[(size_t)(pos + 0) * CCH + ch] = f2bf(v.x + bi);
          Op[(size_t)(pos + 1) * CCH + ch] = f2bf(v.y + bi);
          Op[(size_t)(pos + 2) * CCH + ch] = f2bf(v.z + bi);
          Op[(size_t)(pos + 3) * CCH + ch] = f2bf(v.w + bi);
        } else {  // ch-major (V)
          unsigned short* Op = O + (size_t)b * CCH * HW;
          ushort4 st;
          st.x = f2bf(v.x + bi); st.y = f2bf(v.y + bi);
          st.z = f2bf(v.z + bi); st.w = f2bf(v.w + bi);
          *(ushort4*)&Op[(size_t)ch * HW + pos] = st;
        }
      }
    }
  }
}

// ---------- Flash attention, Ps aliased onto Ks, swizzled LDS, async stage --
// grid (64 bh, 8 qt): same (b,h) blocks spaced by 8 -> same XCD L2 holds K/V.
__global__ __launch_bounds__(256, 4) void attn_kernel(
    const unsigned short* __restrict__ Qt, const unsigned short* __restrict__ Kt,
    const unsigned short* __restrict__ Vc, unsigned short* __restrict__ Ot) {
  int bh = blockIdx.x;
  int b = bh >> 2, h = bh & 3;
  int q0 = blockIdx.y * 128;
  int t = threadIdx.x;
  int w = t >> 6, lane = t & 63, l15 = lane & 15, quad = lane >> 4;
  __shared__ __align__(16) unsigned short SA[64 * 128];   // Ks(64x128) / Ps(128x64) union, 16KB
  __shared__ __align__(16) unsigned short Vs[128 * 64];   // V^T 128d x 64kk, 16KB
  bfrag qf[2][4];
#pragma unroll
  for (int qs = 0; qs < 2; ++qs)
#pragma unroll
    for (int ks = 0; ks < 4; ++ks)
      qf[qs][ks] = *(const bfrag*)&Qt[((size_t)b * HW + q0 + w * 32 + qs * 16 + l15) * CCH +
                                      h * HD + ks * 32 + quad * 8];
  f4 o[2][8] = {};
  float mrow[2] = {-1e30f, -1e30f}, lrow[2] = {0.f, 0.f};
  const float scale = 0.08838834764831845f;  // 1/sqrt(128)
  for (int kt = 0; kt < 16; ++kt) {
    int kk0 = kt * 64;
    __syncthreads();  // prev PV reads of SA/Vs done
#pragma unroll
    for (int j = 0; j < 4; ++j) {  // Ks: 64 rows x 256B; 1KB = 4 rows
      int r = (w * 4 + j) * 4 + (lane >> 4);
      int c = (lane & 15) ^ (r & 7);
      ldg_lds16(&Kt[((size_t)b * HW + kk0 + r) * CCH + h * HD + c * 8],
                &SA[(w * 4 + j) * 512]);
    }
#pragma unroll
    for (int j = 0; j < 4; ++j) {  // Vs: 128 rows x 128B; 1KB = 8 rows
      int r = (w * 4 + j) * 8 + (lane >> 3);
      int c = (lane & 7) ^ (r & 7);
      ldg_lds16(&Vc[((size_t)b * CCH + h * HD + r) * HW + kk0 + c * 8],
                &Vs[(w * 4 + j) * 512]);
    }
    __syncthreads();  // staging visible
    // QK^T: D[m=kk][n=q]
    f4 S[2][4] = {};
#pragma unroll
    for (int ks = 0; ks < 4; ++ks) {
      bfrag kf[4];
#pragma unroll
      for (int mt = 0; mt < 4; ++mt) {
        int r = mt * 16 + l15;
        int cc = (4 * ks + quad) ^ (r & 7);
        kf[mt] = *(const bfrag*)&SA[r * 128 + cc * 8];
      }
#pragma unroll
      for (int qs = 0; qs < 2; ++qs)
#pragma unroll
        for (int mt = 0; mt < 4; ++mt)
          S[qs][mt] = __builtin_amdgcn_mfma_f32_16x16x32_bf16(
              kf[mt], qf[qs][ks], S[qs][mt], 0, 0, 0);
    }
    // online softmax (registers only)
    unsigned pk2[2][8];
#pragma unroll
    for (int qs = 0; qs < 2; ++qs) {
      float vv[16];
#pragma unroll
      for (int mt = 0; mt < 4; ++mt)
#pragma unroll
        for (int r = 0; r < 4; ++r) vv[mt * 4 + r] = S[qs][mt][r] * scale;
      float tm = vv[0];
#pragma unroll
      for (int i = 1; i < 16; ++i) tm = fmaxf(tm, vv[i]);
      tm = fmaxf(tm, __shfl_xor(tm, 16));
      tm = fmaxf(tm, __shfl_xor(tm, 32));
      float mnew = fmaxf(mrow[qs], tm);
      float alpha = __expf(mrow[qs] - mnew);
      float sum = 0.f;
      unsigned short pk[16];
#pragma unroll
      for (int i = 0; i < 16; ++i) {
        float p = __expf(vv[i] - mnew);
        sum += p;
        pk[i] = f2bf(p);
      }
      sum += __shfl_xor(sum, 16);
      sum += __shfl_xor(sum, 32);
      lrow[qs] = lrow[qs] * alpha + sum;
      mrow[qs] = mnew;
#pragma unroll
      for (int dt = 0; dt < 8; ++dt) o[qs][dt] *= alpha;
#pragma unroll
      for (int mt = 0; mt < 4; ++mt) {
        pk2[qs][mt * 2 + 0] = pack2(pk[mt * 4 + 0], pk[mt * 4 + 1]);
        pk2[qs][mt * 2 + 1] = pack2(pk[mt * 4 + 2], pk[mt * 4 + 3]);
      }
    }
    __syncthreads();  // all QK^T reads of SA done
    // P -> SA (as Ps[128 q][64 kk], swizzled)
#pragma unroll
    for (int qs = 0; qs < 2; ++qs) {
      int rq = w * 32 + qs * 16 + l15;
#pragma unroll
      for (int mt = 0; mt < 4; ++mt) {
        int cc = (2 * mt + (quad >> 1)) ^ (rq & 7);
        uint2 u;
        u.x = pk2[qs][mt * 2 + 0];
        u.y = pk2[qs][mt * 2 + 1];
        *(uint2*)&SA[rq * 64 + cc * 8 + (quad & 1) * 4] = u;
      }
    }
    __syncthreads();  // Ps visible
    // PV: D[m=d][n=q]
#pragma unroll
    for (int ks = 0; ks < 2; ++ks) {
      bfrag pf[2];
#pragma unroll
      for (int qs = 0; qs < 2; ++qs) {
        int rq = w * 32 + qs * 16 + l15;
        int cc = (4 * ks + quad) ^ (rq & 7);
        pf[qs] = *(const bfrag*)&SA[rq * 64 + cc * 8];
      }
#pragma unroll
      for (int dt = 0; dt < 8; ++dt) {
        int r = dt * 16 + l15;
        int cc = (4 * ks + quad) ^ (r & 7);
        bfrag vf = *(const bfrag*)&Vs[r * 64 + cc * 8];
#pragma unroll
        for (int qs = 0; qs < 2; ++qs)
          o[qs][dt] = __builtin_amdgcn_mfma_f32_16x16x32_bf16(
              vf, pf[qs], o[qs][dt], 0, 0, 0);
      }
    }
  }
#pragma unroll
  for (int qs = 0; qs < 2; ++qs) {
    float inv = 1.f / lrow[qs];
    int q = q0 + w * 32 + qs * 16 + l15;
#pragma unroll
    for (int dt = 0; dt < 8; ++dt) {
      f4 v = o[qs][dt];
      ushort4 st;
      st.x = f2bf(v.x * inv); st.y = f2bf(v.y * inv);
      st.z = f2bf(v.z * inv); st.w = f2bf(v.w * inv);
      *(ushort4*)&Ot[((size_t)b * HW + q) * CCH + h * HD + dt * 16 + quad * 4] = st;
    }
  }
}

extern "C" void kernel_launch(void* const* d_in, const int* in_sizes, int n_in,
                              void* d_out, int out_size, void* d_ws,
                              size_t ws_size, hipStream_t stream) {
  const float* x = (const float*)d_in[0];
  const float* gamma = (const float*)d_in[1];
  const float* beta = (const float*)d_in[2];
  const float* wq = (const float*)d_in[3];
  const float* bq = (const float*)d_in[4];
  const float* wk = (const float*)d_in[5];
  const float* bk = (const float*)d_in[6];
  const float* wv = (const float*)d_in[7];
  const float* bv = (const float*)d_in[8];
  const float* wp = (const float*)d_in[9];
  const float* bp = (const float*)d_in[10];

  const size_t TS = (size_t)BATCH * HW * CCH;
  unsigned short* wB = (unsigned short*)d_ws;  // [4][512][512] bf16 (q,k,v,p)
  unsigned short* hn = wB + (size_t)4 * CCH * CCH;
  unsigned short* Qt = hn + TS;
  unsigned short* Kt = Qt + TS;
  unsigned short* Vc = Kt + TS;
  unsigned short* Ot = hn;  // reuse hn after QKV

  wcvt_kernel<<<dim3(256, 4), 256, 0, stream>>>(wq, wk, wv, wp, wB);
  gn_kernel<<<dim3(BATCH * 32), 256, 0, stream>>>(x, gamma, beta, hn);
  mm_kernel<0><<<dim3(8, 12, BATCH), 256, 0, stream>>>(
      hn, wB, bq, bk, bv, nullptr, Qt, Kt, Vc, nullptr);
  attn_kernel<<<dim3(64, 8), 256, 0, stream>>>(Qt, Kt, Vc, Ot);
  mm_kernel<1><<<dim3(8, 4, BATCH), 256, 0, stream>>>(
      Ot, wB + (size_t)3 * CCH * CCH, bp, bp, bp, x, nullptr, nullptr, nullptr,
      (float*)d_out);
}

// Round 4
// 240.151 us; speedup vs baseline: 1.4532x; 1.4532x over previous
//
#include <hip/hip_runtime.h>
#include <math.h>

#define CCH 512
#define NH 4
#define HD 128
#define HW 1024
#define BATCH 16
#define EPS 1e-5f

typedef __attribute__((ext_vector_type(8))) short bfrag;   // 8 bf16 = 4 VGPRs
typedef __attribute__((ext_vector_type(4))) float f4;

static __device__ __forceinline__ unsigned short f2bf(float f) {
  union { float f; unsigned u; } v;
  v.f = f;
  unsigned r = v.u + 0x7fff + ((v.u >> 16) & 1);  // RNE
  return (unsigned short)(r >> 16);
}
static __device__ __forceinline__ unsigned pack2(unsigned short a, unsigned short b) {
  return (unsigned)a | ((unsigned)b << 16);
}
// async global->LDS, 16B/lane. LDS dest = wave-uniform base + lane*16.
static __device__ __forceinline__ void ldg_lds16(const unsigned short* g,
                                                 unsigned short* l) {
  __builtin_amdgcn_global_load_lds(
      (const __attribute__((address_space(1))) unsigned int*)g,
      (__attribute__((address_space(3))) unsigned int*)l, 16, 0, 0);
}

// ---------- weights fp32 -> bf16 (4 matrices stacked) ----------
__global__ __launch_bounds__(256) void wcvt_kernel(const float* __restrict__ s0,
                                                   const float* __restrict__ s1,
                                                   const float* __restrict__ s2,
                                                   const float* __restrict__ s3,
                                                   unsigned short* __restrict__ d) {
  const float* srcs[4] = {s0, s1, s2, s3};
  const float* s = srcs[blockIdx.y];
  unsigned short* dp = d + (size_t)blockIdx.y * CCH * CCH;
  int i = blockIdx.x * 256 + threadIdx.x;
  f4 v = ((const f4*)s)[i];
  ushort4 o;
  o.x = f2bf(v.x); o.y = f2bf(v.y); o.z = f2bf(v.z); o.w = f2bf(v.w);
  ((ushort4*)dp)[i] = o;
}

// ---------- GroupNorm -> position-major bf16 hn_t[b][hw][c] ----------
__global__ __launch_bounds__(256) void gn_kernel(const float* __restrict__ x,
                                                 const float* __restrict__ gamma,
                                                 const float* __restrict__ beta,
                                                 unsigned short* __restrict__ hn) {
  int b = blockIdx.x >> 5, g = blockIdx.x & 31;
  const float* xp = x + ((size_t)b * CCH + g * 16) * HW;
  int t = threadIdx.x;
  float s = 0.f, ss = 0.f;
  const f4* xp4 = (const f4*)xp;
  for (int i = t; i < 4096; i += 256) {
    f4 v = xp4[i];
    s += v.x + v.y + v.z + v.w;
    ss += v.x * v.x + v.y * v.y + v.z * v.z + v.w * v.w;
  }
#pragma unroll
  for (int off = 32; off > 0; off >>= 1) {
    s += __shfl_xor(s, off);
    ss += __shfl_xor(ss, off);
  }
  __shared__ float rs[4], rss[4];
  int w = t >> 6;
  if ((t & 63) == 0) { rs[w] = s; rss[w] = ss; }
  __syncthreads();
  s = rs[0] + rs[1] + rs[2] + rs[3];
  ss = rss[0] + rss[1] + rss[2] + rss[3];
  const float invn = 1.f / (16 * HW);
  float mean = s * invn;
  float var = ss * invn - mean * mean;
  float rstd = rsqrtf(var + EPS);
  float a_[16], b_[16];
#pragma unroll
  for (int c = 0; c < 16; ++c) {
    float gm = gamma[g * 16 + c] * rstd;
    a_[c] = gm;
    b_[c] = beta[g * 16 + c] - mean * gm;
  }
#pragma unroll
  for (int i = 0; i < 4; ++i) {
    int p = t + 256 * i;
    unsigned short tv[16];
#pragma unroll
    for (int c = 0; c < 16; ++c) tv[c] = f2bf(xp[c * HW + p] * a_[c] + b_[c]);
    uint4 u0, u1;
    u0.x = pack2(tv[0], tv[1]);  u0.y = pack2(tv[2], tv[3]);
    u0.z = pack2(tv[4], tv[5]);  u0.w = pack2(tv[6], tv[7]);
    u1.x = pack2(tv[8], tv[9]);  u1.y = pack2(tv[10], tv[11]);
    u1.z = pack2(tv[12], tv[13]); u1.w = pack2(tv[14], tv[15]);
    unsigned short* dst = hn + ((size_t)b * HW + p) * CCH + g * 16;
    *(uint4*)dst = u0;
    *(uint4*)(dst + 8) = u1;
  }
}

// ---------- MFMA GEMM, m97-style staging (global_load_lds + XOR swizzle) ---
// D[pos][ch] = sum_k Xt[b][pos][k] * W[ch][k] + bias
// PROJ=0: fused QKV (c0g in [0,1536)): mat 0,1 -> pos-major bf16 (Q,K);
//         mat 2 -> ch-major bf16 (V).
// PROJ=1: fp32 ch-major out + residual.
template <int PROJ>
__global__ __launch_bounds__(256, 3) void mm_kernel(
    const unsigned short* __restrict__ Xt, const unsigned short* __restrict__ Wb,
    const float* __restrict__ b0, const float* __restrict__ b1,
    const float* __restrict__ b2, const float* __restrict__ resid,
    unsigned short* __restrict__ O0, unsigned short* __restrict__ O1,
    unsigned short* __restrict__ O2, float* __restrict__ Ofp) {
  int b = blockIdx.z;
  int p0 = blockIdx.x * 128;
  int c0g = blockIdx.y * 128;
  __shared__ __align__(16) unsigned short Xs[128 * 32];
  __shared__ __align__(16) unsigned short Ws[128 * 32];
  int t = threadIdx.x;
  int w = t >> 6, lane = t & 63, l15 = lane & 15, quad = lane >> 4;
  int wp = (w & 1) * 64, wc = (w >> 1) * 64;
  const unsigned short* Xb = Xt + (size_t)b * HW * CCH;
  const unsigned short* Wr = Wb + (size_t)c0g * CCH;
  f4 acc[4][4] = {};
  for (int k0 = 0; k0 < CCH; k0 += 32) {
    __syncthreads();
#pragma unroll
    for (int j = 0; j < 2; ++j) {
      int chk = w * 2 + j;             // 1KB chunk = 16 rows x 64B
      int r = chk * 16 + (lane >> 2);
      int c = (lane & 3) ^ (r & 3);    // XOR swizzle
      ldg_lds16(&Xb[(size_t)(p0 + r) * CCH + k0 + c * 8], &Xs[chk * 512]);
      ldg_lds16(&Wr[(size_t)r * CCH + k0 + c * 8], &Ws[chk * 512]);
    }
    __syncthreads();
    bfrag af[4], bf[4];
#pragma unroll
    for (int pt = 0; pt < 4; ++pt) {
      int r = wp + pt * 16 + l15;
      af[pt] = *(const bfrag*)&Xs[r * 32 + (quad ^ (r & 3)) * 8];
    }
#pragma unroll
    for (int ct = 0; ct < 4; ++ct) {
      int r = wc + ct * 16 + l15;
      bf[ct] = *(const bfrag*)&Ws[r * 32 + (quad ^ (r & 3)) * 8];
    }
#pragma unroll
    for (int pt = 0; pt < 4; ++pt)
#pragma unroll
      for (int ct = 0; ct < 4; ++ct)
        acc[pt][ct] = __builtin_amdgcn_mfma_f32_16x16x32_bf16(
            af[pt], bf[ct], acc[pt][ct], 0, 0, 0);
  }
  if (PROJ) {
#pragma unroll
    for (int ct = 0; ct < 4; ++ct) {
      int ch = c0g + wc + ct * 16 + l15;
      float bi = b0[ch];
#pragma unroll
      for (int pt = 0; pt < 4; ++pt) {
        int pos = p0 + wp + pt * 16 + quad * 4;
        f4 v = acc[pt][ct];
        size_t off = (size_t)b * CCH * HW + (size_t)ch * HW + pos;
        float4 rv = *(const float4*)&resid[off];
        float4 st;
        st.x = v.x + bi + rv.x; st.y = v.y + bi + rv.y;
        st.z = v.z + bi + rv.z; st.w = v.w + bi + rv.w;
        *(float4*)&Ofp[off] = st;
      }
    }
  } else {
    int mat = c0g >> 9;
    int c0 = c0g & 511;
    const float* bias = mat == 0 ? b0 : (mat == 1 ? b1 : b2);
    unsigned short* O = mat == 0 ? O0 : (mat == 1 ? O1 : O2);
#pragma unroll
    for (int ct = 0; ct < 4; ++ct) {
      int ch = c0 + wc + ct * 16 + l15;
      float bi = bias[ch];
#pragma unroll
      for (int pt = 0; pt < 4; ++pt) {
        int pos = p0 + wp + pt * 16 + quad * 4;
        f4 v = acc[pt][ct];
        if (mat < 2) {  // pos-major
          unsigned short* Op = O + (size_t)b * HW * CCH;
          Op[(size_t)(pos + 0) * CCH + ch] = f2bf(v.x + bi);
          Op[(size_t)(pos + 1) * CCH + ch] = f2bf(v.y + bi);
          Op[(size_t)(pos + 2) * CCH + ch] = f2bf(v.z + bi);
          Op[(size_t)(pos + 3) * CCH + ch] = f2bf(v.w + bi);
        } else {  // ch-major (V)
          unsigned short* Op = O + (size_t)b * CCH * HW;
          ushort4 st;
          st.x = f2bf(v.x + bi); st.y = f2bf(v.y + bi);
          st.z = f2bf(v.z + bi); st.w = f2bf(v.w + bi);
          *(ushort4*)&Op[(size_t)ch * HW + pos] = st;
        }
      }
    }
  }
}

// ---------- Flash attention: 512 threads = 8 waves x 16 queries ----------
// Per-wave regs ~100 (o 32 + qf 16 + temps) -> no spills, 16 waves/CU.
// grid (64 bh, 8 qt): same (b,h) blocks spaced by 8 -> same XCD L2 holds K/V.
__global__ __launch_bounds__(512, 3) void attn_kernel(
    const unsigned short* __restrict__ Qt, const unsigned short* __restrict__ Kt,
    const unsigned short* __restrict__ Vc, unsigned short* __restrict__ Ot) {
  int bh = blockIdx.x;
  int b = bh >> 2, h = bh & 3;
  int q0 = blockIdx.y * 128;
  int t = threadIdx.x;
  int w = t >> 6, lane = t & 63, l15 = lane & 15, quad = lane >> 4;
  __shared__ __align__(16) unsigned short SA[64 * 128];   // Ks(64x128)/Ps(128x64) union, 16KB
  __shared__ __align__(16) unsigned short Vs[128 * 64];   // V^T 128d x 64kk, 16KB
  int rq = w * 16 + l15;  // this lane's q row within the 128-tile
  bfrag qf[4];
#pragma unroll
  for (int ks = 0; ks < 4; ++ks)
    qf[ks] = *(const bfrag*)&Qt[((size_t)b * HW + q0 + rq) * CCH +
                                h * HD + ks * 32 + quad * 8];
  f4 o[8] = {};
  float mrow = -1e30f, lrow = 0.f;
  const float scale = 0.08838834764831845f;  // 1/sqrt(128)
  for (int kt = 0; kt < 16; ++kt) {
    int kk0 = kt * 64;
    __syncthreads();  // prev PV reads of SA/Vs done
#pragma unroll
    for (int j = 0; j < 2; ++j) {  // Ks: 16 chunks of 1KB (4 rows x 256B)
      int chk = w * 2 + j;
      int r = chk * 4 + (lane >> 4);
      int c = (lane & 15) ^ (r & 7);
      ldg_lds16(&Kt[((size_t)b * HW + kk0 + r) * CCH + h * HD + c * 8],
                &SA[chk * 512]);
    }
#pragma unroll
    for (int j = 0; j < 2; ++j) {  // Vs: 16 chunks of 1KB (8 rows x 128B)
      int chk = w * 2 + j;
      int r = chk * 8 + (lane >> 3);
      int c = (lane & 7) ^ (r & 7);
      ldg_lds16(&Vc[((size_t)b * CCH + h * HD + r) * HW + kk0 + c * 8],
                &Vs[chk * 512]);
    }
    __syncthreads();  // staging visible
    // QK^T: D[m=kk][n=q]
    f4 S[4] = {};
#pragma unroll
    for (int ks = 0; ks < 4; ++ks) {
      bfrag kf[4];
#pragma unroll
      for (int mt = 0; mt < 4; ++mt) {
        int r = mt * 16 + l15;
        int cc = (4 * ks + quad) ^ (r & 7);
        kf[mt] = *(const bfrag*)&SA[r * 128 + cc * 8];
      }
#pragma unroll
      for (int mt = 0; mt < 4; ++mt)
        S[mt] = __builtin_amdgcn_mfma_f32_16x16x32_bf16(kf[mt], qf[ks], S[mt],
                                                        0, 0, 0);
    }
    // online softmax (registers only)
    float vv[16];
#pragma unroll
    for (int mt = 0; mt < 4; ++mt)
#pragma unroll
      for (int r = 0; r < 4; ++r) vv[mt * 4 + r] = S[mt][r] * scale;
    float tm = vv[0];
#pragma unroll
    for (int i = 1; i < 16; ++i) tm = fmaxf(tm, vv[i]);
    tm = fmaxf(tm, __shfl_xor(tm, 16));
    tm = fmaxf(tm, __shfl_xor(tm, 32));
    float mnew = fmaxf(mrow, tm);
    float alpha = __expf(mrow - mnew);
    float sum = 0.f;
    unsigned short pk[16];
#pragma unroll
    for (int i = 0; i < 16; ++i) {
      float p = __expf(vv[i] - mnew);
      sum += p;
      pk[i] = f2bf(p);
    }
    sum += __shfl_xor(sum, 16);
    sum += __shfl_xor(sum, 32);
    lrow = lrow * alpha + sum;
    mrow = mnew;
#pragma unroll
    for (int dt = 0; dt < 8; ++dt) o[dt] *= alpha;
    unsigned pk2[8];
#pragma unroll
    for (int mt = 0; mt < 4; ++mt) {
      pk2[mt * 2 + 0] = pack2(pk[mt * 4 + 0], pk[mt * 4 + 1]);
      pk2[mt * 2 + 1] = pack2(pk[mt * 4 + 2], pk[mt * 4 + 3]);
    }
    __syncthreads();  // all QK^T reads of SA done
    // P -> SA (as Ps[128 q][64 kk], swizzled)
#pragma unroll
    for (int mt = 0; mt < 4; ++mt) {
      int cc = (2 * mt + (quad >> 1)) ^ (rq & 7);
      uint2 u;
      u.x = pk2[mt * 2 + 0];
      u.y = pk2[mt * 2 + 1];
      *(uint2*)&SA[rq * 64 + cc * 8 + (quad & 1) * 4] = u;
    }
    __syncthreads();  // Ps visible
    // PV: D[m=d][n=q]
#pragma unroll
    for (int ks = 0; ks < 2; ++ks) {
      int cq = (4 * ks + quad) ^ (rq & 7);
      bfrag pf = *(const bfrag*)&SA[rq * 64 + cq * 8];
#pragma unroll
      for (int dt = 0; dt < 8; ++dt) {
        int r = dt * 16 + l15;
        int cc = (4 * ks + quad) ^ (r & 7);
        bfrag vf = *(const bfrag*)&Vs[r * 64 + cc * 8];
        o[dt] = __builtin_amdgcn_mfma_f32_16x16x32_bf16(vf, pf, o[dt], 0, 0, 0);
      }
    }
  }
  float inv = 1.f / lrow;
  int q = q0 + rq;
#pragma unroll
  for (int dt = 0; dt < 8; ++dt) {
    f4 v = o[dt];
    ushort4 st;
    st.x = f2bf(v.x * inv); st.y = f2bf(v.y * inv);
    st.z = f2bf(v.z * inv); st.w = f2bf(v.w * inv);
    *(ushort4*)&Ot[((size_t)b * HW + q) * CCH + h * HD + dt * 16 + quad * 4] = st;
  }
}

extern "C" void kernel_launch(void* const* d_in, const int* in_sizes, int n_in,
                              void* d_out, int out_size, void* d_ws,
                              size_t ws_size, hipStream_t stream) {
  const float* x = (const float*)d_in[0];
  const float* gamma = (const float*)d_in[1];
  const float* beta = (const float*)d_in[2];
  const float* wq = (const float*)d_in[3];
  const float* bq = (const float*)d_in[4];
  const float* wk = (const float*)d_in[5];
  const float* bk = (const float*)d_in[6];
  const float* wv = (const float*)d_in[7];
  const float* bv = (const float*)d_in[8];
  const float* wp = (const float*)d_in[9];
  const float* bp = (const float*)d_in[10];

  const size_t TS = (size_t)BATCH * HW * CCH;
  unsigned short* wB = (unsigned short*)d_ws;  // [4][512][512] bf16 (q,k,v,p)
  unsigned short* hn = wB + (size_t)4 * CCH * CCH;
  unsigned short* Qt = hn + TS;
  unsigned short* Kt = Qt + TS;
  unsigned short* Vc = Kt + TS;
  unsigned short* Ot = hn;  // reuse hn after QKV

  wcvt_kernel<<<dim3(256, 4), 256, 0, stream>>>(wq, wk, wv, wp, wB);
  gn_kernel<<<dim3(BATCH * 32), 256, 0, stream>>>(x, gamma, beta, hn);
  mm_kernel<0><<<dim3(8, 12, BATCH), 256, 0, stream>>>(
      hn, wB, bq, bk, bv, nullptr, Qt, Kt, Vc, nullptr);
  attn_kernel<<<dim3(64, 8), 512, 0, stream>>>(Qt, Kt, Vc, Ot);
  mm_kernel<1><<<dim3(8, 4, BATCH), 256, 0, stream>>>(
      Ot, wB + (size_t)3 * CCH * CCH, bp, bp, bp, x, nullptr, nullptr, nullptr,
      (float*)d_out);
}